// Round 11
// baseline (356.282 us; speedup 1.0000x reference)
//
#include <hip/hip_runtime.h>
#include <hip/hip_bf16.h>
#include <math.h>

typedef __bf16 bf16;
typedef __attribute__((ext_vector_type(8))) __bf16 bf16x8;
typedef __attribute__((ext_vector_type(4))) __bf16 bf16x4;
typedef __attribute__((ext_vector_type(4))) float f32x4;

#define NB 8
#define SEQ 1024
#define DIM 768
#define ROWS (NB*SEQ)

__device__ __forceinline__ float gelu_exact(float x){
  return 0.5f * x * (1.0f + erff(x * 0.70710678118654752440f));
}

__device__ __forceinline__ void gload_lds16(const void* g, void* l){
  __builtin_amdgcn_global_load_lds((const __attribute__((address_space(1))) void*)g,
                                   (__attribute__((address_space(3))) void*)l, 16, 0, 0);
}

// ---------------- embed + pos ----------------
__global__ __launch_bounds__(192)
void k_embed(const int* __restrict__ idx, const float* __restrict__ emb,
             const float* __restrict__ pos, bf16* __restrict__ xo){
  const int row = blockIdx.x;           // b*SEQ + s
  const int s = row & (SEQ-1);
  const int tok = idx[row];
  const float* e = emb + (long)tok*DIM;
  const float* p = pos + (long)s*DIM;
  bf16* o = xo + (long)row*DIM;
  const int tid = threadIdx.x;          // 0..191, 4 floats each
  f32x4 ev = *(const f32x4*)(e + tid*4);
  f32x4 pv = *(const f32x4*)(p + tid*4);
  bf16x4 ov;
  ov[0]=(bf16)(ev[0]+pv[0]); ov[1]=(bf16)(ev[1]+pv[1]);
  ov[2]=(bf16)(ev[2]+pv[2]); ov[3]=(bf16)(ev[3]+pv[3]);
  *(bf16x4*)(o + tid*4) = ov;
}

// ---------------- fused weight transposes: 5x fp32 [768][768] -> bf16 [768][768]^T ----------------
__global__ __launch_bounds__(256)
void k_transpose_w(const float* __restrict__ Wq, const float* __restrict__ Wk,
                   const float* __restrict__ Wv, const float* __restrict__ W1,
                   const float* __restrict__ W2,
                   bf16* __restrict__ Wqkvt, bf16* __restrict__ W1t, bf16* __restrict__ W2t){
  __shared__ float t[32][33];
  const int z = blockIdx.z;
  const float* src = (z==0)?Wq:(z==1)?Wk:(z==2)?Wv:(z==3)?W1:W2;
  bf16* dst = (z<3) ? (Wqkvt + (size_t)z*768*768) : ((z==3)?W1t:W2t);
  const int n0 = blockIdx.x*32, k0 = blockIdx.y*32;
  const int tx = threadIdx.x, ty = threadIdx.y;   // (32,8)
  #pragma unroll
  for (int i=0;i<4;i++)
    t[ty+i*8][tx] = src[(long)(k0+ty+i*8)*768 + n0 + tx];
  __syncthreads();
  #pragma unroll
  for (int i=0;i<4;i++)
    dst[(long)(n0+ty+i*8)*768 + k0 + tx] = (bf16)t[tx][ty+i*8];
}

// ---------------- v[b,s,d] (inside qkv, col offset 1536) -> vT[b,d,s] ----------------
__global__ __launch_bounds__(256)
void k_transpose_v(const bf16* __restrict__ qkv, bf16* __restrict__ vT){
  __shared__ bf16 t[32][33];
  const int b = blockIdx.z;
  const int s0 = blockIdx.x*32, d0 = blockIdx.y*32;
  const int tx = threadIdx.x, ty = threadIdx.y;
  const bf16* src = qkv + (long)b*SEQ*2304 + 1536;
  bf16* dst = vT + (long)b*DIM*SEQ;
  #pragma unroll
  for (int i=0;i<4;i++)
    t[ty+i*8][tx] = src[(long)(s0+ty+i*8)*2304 + d0 + tx];
  __syncthreads();
  #pragma unroll
  for (int i=0;i<4;i++)
    dst[(long)(d0+ty+i*8)*SEQ + s0 + tx] = t[tx][ty+i*8];
}

// ============ 128x128 / BK=32 / 4-wave 2-phase GEMM ============
// C[M][N] = A[M][K] * Bt[N][K]^T
// EPI: 0 = bf16 store; 1 = bias+gelu->bf16;
//      3 = key-masked exp(scale*x)->bf16 + fused ATOMIC row-sum (sums the
//          bf16-rounded P for exact parity with what PV's MFMA consumes)
//      4 = divide by rowsum[m] -> bf16 (completes softmax after PV)
// __launch_bounds__(256,2): post-timing-validated. (256,3) RACED (r6) — do not raise.
// XCD swizzle (T1): bijective remap within the xy-slice; caller guarantees gx*gy % 8 == 0.
template<int EPI>
__global__ __launch_bounds__(256, 2)
void k_gemm2p(const bf16* __restrict__ A, int lda, long sA,
              const bf16* __restrict__ Bt, int ldb, long sB,
              void* __restrict__ Cv, int ldc, long sC,
              int K,
              const float* __restrict__ bias,
              const int* __restrict__ mask, int maskStride,
              float* __restrict__ rowsum,
              float scale)
{
  __shared__ __align__(16) bf16 As[2][128][32];
  __shared__ __align__(16) bf16 Bs[2][128][32];

  const int bz = blockIdx.z;
  A  += (long)bz * sA;
  Bt += (long)bz * sB;

  // XCD-bijective swizzle within xy-slice (nwg % 8 == 0 guaranteed by caller)
  const int gx = gridDim.x;
  const int nwg = gx * gridDim.y;
  const int chunk = nwg >> 3;
  const int flat = blockIdx.y*gx + blockIdx.x;
  const int logical = (flat & 7)*chunk + (flat >> 3);
  const int m0 = (logical % gx) * 128;
  const int n0 = (logical / gx) * 128;

  const int tid  = threadIdx.x;
  const int lane = tid & 63;
  const int w    = tid >> 6;

  const int st_row = w*16 + (lane>>2);
  const int st_col = (lane&3)*8;
  const bf16* Ag0 = A  + (long)(m0 + st_row)*lda + st_col;
  const bf16* Bg0 = Bt + (long)(n0 + st_row)*ldb + st_col;

  const int nk = K >> 5;

  f32x4 acc[4][4];
  const f32x4 zero = {0.f,0.f,0.f,0.f};
  #pragma unroll
  for (int i=0;i<4;i++)
    #pragma unroll
    for (int j=0;j<4;j++) acc[i][j] = zero;

  const int wr = (w>>1)*64;
  const int wc = (w&1)*64;
  const int fr = lane & 15;
  const int fk = (lane>>4)*8;

  {
    char* lA = (char*)&As[0][0][0] + w*1024;
    char* lB = (char*)&Bs[0][0][0] + w*1024;
    gload_lds16(Ag0,                lA);
    gload_lds16(Ag0 + (long)64*lda, lA + 4096);
    gload_lds16(Bg0,                lB);
    gload_lds16(Bg0 + (long)64*ldb, lB + 4096);
  }

  int buf = 0;
  for (int kt=0; kt<nk; kt++){
    __syncthreads();
    if (kt+1 < nk){
      const bf16* Ag = Ag0 + (kt+1)*32;
      const bf16* Bg = Bg0 + (kt+1)*32;
      char* lA = (char*)&As[buf^1][0][0] + w*1024;
      char* lB = (char*)&Bs[buf^1][0][0] + w*1024;
      gload_lds16(Ag,                lA);
      gload_lds16(Ag + (long)64*lda, lA + 4096);
      gload_lds16(Bg,                lB);
      gload_lds16(Bg + (long)64*ldb, lB + 4096);
    }
    bf16x8 af[4], bfv[4];
    #pragma unroll
    for (int t=0;t<4;t++){
      af[t]  = *(const bf16x8*)&As[buf][wr + t*16 + fr][fk];
      bfv[t] = *(const bf16x8*)&Bs[buf][wc + t*16 + fr][fk];
    }
    #pragma unroll
    for (int mt=0;mt<4;mt++)
      #pragma unroll
      for (int nt=0;nt<4;nt++)
        acc[mt][nt] = __builtin_amdgcn_mfma_f32_16x16x32_bf16(af[mt], bfv[nt], acc[mt][nt], 0, 0, 0);
    buf ^= 1;
  }

  // epilogue: C/D layout col=lane&15, row=(lane>>4)*4+reg  [HW-verified]
  const int cm0 = m0 + wr + ((lane>>4)<<2);
  const int cn0 = n0 + wc + fr;
  const long cb = (long)bz * sC;

  if (EPI == 3){
    const int* mk = mask + (long)bz*maskStride;
    float rowpart[4][4];   // [mt][r] partial row sums over this lane's 4 cols
    #pragma unroll
    for (int mt=0;mt<4;mt++)
      #pragma unroll
      for (int r=0;r<4;r++) rowpart[mt][r] = 0.f;
    #pragma unroll
    for (int mt=0;mt<4;mt++){
      #pragma unroll
      for (int nt=0;nt<4;nt++){
        #pragma unroll
        for (int r=0;r<4;r++){
          const int m = cm0 + mt*16 + r;
          const int n = cn0 + nt*16;
          float p = (mk[n] != 0) ? expf(acc[mt][nt][r]*scale) : 0.0f;
          bf16 pb = (bf16)p;
          ((bf16*)Cv)[cb + (long)m*ldc + n] = pb;
          rowpart[mt][r] += (float)pb;
        }
      }
    }
    // reduce across the 16 col-lanes of each quarter-group, then 1 atomic/row
    #pragma unroll
    for (int mt=0;mt<4;mt++){
      #pragma unroll
      for (int r=0;r<4;r++){
        float v = rowpart[mt][r];
        v += __shfl_xor(v, 1);
        v += __shfl_xor(v, 2);
        v += __shfl_xor(v, 4);
        v += __shfl_xor(v, 8);
        if ((lane & 15) == 0)
          atomicAdd(&rowsum[(long)bz*SEQ + cm0 + mt*16 + r], v);
      }
    }
    return;
  }

  #pragma unroll
  for (int mt=0;mt<4;mt++){
    #pragma unroll
    for (int r=0;r<4;r++){
      float rinv = 1.0f;
      if (EPI == 4)
        rinv = 1.0f / rowsum[(long)bz*SEQ + cm0 + mt*16 + r];
      #pragma unroll
      for (int nt=0;nt<4;nt++){
        const int m = cm0 + mt*16 + r;
        const int n = cn0 + nt*16;
        const long o = cb + (long)m*ldc + n;
        float c = acc[mt][nt][r];
        if (EPI == 0){
          ((bf16*)Cv)[o] = (bf16)c;
        } else if (EPI == 1){
          ((bf16*)Cv)[o] = (bf16)gelu_exact(c + bias[n]);
        } else { // EPI == 4
          ((bf16*)Cv)[o] = (bf16)(c * rinv);
        }
      }
    }
  }
}

// ---------------- layernorm (two-pass, matches reference) ----------------
template<int IN_BF16, int OUT_BF16>
__global__ __launch_bounds__(256)
void k_layernorm(const void* __restrict__ Xv, const float* __restrict__ g,
                 const float* __restrict__ b, void* __restrict__ Yv){
  __shared__ float red[4];
  __shared__ float red2[4];
  const int row = blockIdx.x;
  const int tid = threadIdx.x;
  float v0, v1, v2;
  if (IN_BF16){
    const bf16* x = (const bf16*)Xv + (long)row*DIM;
    v0=(float)x[tid]; v1=(float)x[tid+256]; v2=(float)x[tid+512];
  } else {
    const float* x = (const float*)Xv + (long)row*DIM;
    v0=x[tid]; v1=x[tid+256]; v2=x[tid+512];
  }
  float s = v0+v1+v2;
  #pragma unroll
  for (int o=32;o>0;o>>=1) s += __shfl_xor(s, o);
  if ((tid&63)==0) red[tid>>6] = s;
  __syncthreads();
  s = red[0]+red[1]+red[2]+red[3];
  const float mu = s * (1.0f/768.0f);
  const float d0=v0-mu, d1=v1-mu, d2=v2-mu;
  float q = d0*d0+d1*d1+d2*d2;
  #pragma unroll
  for (int o=32;o>0;o>>=1) q += __shfl_xor(q, o);
  if ((tid&63)==0) red2[tid>>6] = q;
  __syncthreads();
  q = red2[0]+red2[1]+red2[2]+red2[3];
  const float r = rsqrtf(q*(1.0f/768.0f) + 1e-5f);
  const float y0 = d0*r*g[tid]     + b[tid];
  const float y1 = d1*r*g[tid+256] + b[tid+256];
  const float y2 = d2*r*g[tid+512] + b[tid+512];
  if (OUT_BF16){
    bf16* Y = (bf16*)Yv;
    Y[(long)row*DIM+tid]=(bf16)y0; Y[(long)row*DIM+tid+256]=(bf16)y1; Y[(long)row*DIM+tid+512]=(bf16)y2;
  } else {
    float* Y = (float*)Yv;
    Y[(long)row*DIM+tid]=y0; Y[(long)row*DIM+tid+256]=y1; Y[(long)row*DIM+tid+512]=y2;
  }
}

extern "C" void kernel_launch(void* const* d_in, const int* in_sizes, int n_in,
                              void* d_out, int out_size, void* d_ws, size_t ws_size,
                              hipStream_t stream)
{
  (void)in_sizes; (void)n_in; (void)out_size; (void)ws_size;
  const int*   idx  = (const int*)d_in[0];
  const int*   am   = (const int*)d_in[1];
  const float* emb  = (const float*)d_in[2];
  const float* pos  = (const float*)d_in[3];
  const float* Wq   = (const float*)d_in[4];
  const float* Wk   = (const float*)d_in[5];
  const float* Wv   = (const float*)d_in[6];
  const float* ln1g = (const float*)d_in[7];
  const float* ln1b = (const float*)d_in[8];
  const float* W1   = (const float*)d_in[9];
  const float* b1   = (const float*)d_in[10];
  const float* W2   = (const float*)d_in[11];
  const float* b2   = (const float*)d_in[12];
  const float* ln2g = (const float*)d_in[13];
  const float* ln2b = (const float*)d_in[14];

  char* ws = (char*)d_ws;
  size_t off = 0;
  auto take = [&](size_t bytes)->char*{
    char* p = ws + off;
    off += (bytes + 255) & ~(size_t)255;
    return p;
  };
  bf16*  Wqkvt = (bf16*) take((size_t)2304*768*2);
  bf16*  W1t   = (bf16*) take((size_t)768*768*2);
  bf16*  W2t   = (bf16*) take((size_t)768*768*2);
  bf16*  xbf   = (bf16*) take((size_t)ROWS*DIM*2);
  bf16*  qkv   = (bf16*) take((size_t)ROWS*2304*2);
  bf16*  vT    = (bf16*) take((size_t)NB*DIM*SEQ*2);
  bf16*  P     = (bf16*) take((size_t)NB*SEQ*SEQ*2);   // unnormalized softmax numerators
  float* rsum  = (float*)take((size_t)ROWS*4);         // atomic row sums (zeroed below)
  bf16*  aout  = (bf16*) take((size_t)ROWS*DIM*2);     // attention out (bf16)
  bf16*  x1    = (bf16*) take((size_t)ROWS*DIM*2);
  bf16*  h1    = (bf16*) take((size_t)ROWS*DIM*2);
  bf16*  h2    = (bf16*) take((size_t)ROWS*DIM*2);     // gelu(h1 W2 + b2) bf16
  float* out   = (float*)d_out;

  // rowsum accumulator must be zero each call (ws is re-poisoned to 0xAA)
  hipMemsetAsync(rsum, 0, (size_t)ROWS*4, stream);

  k_transpose_w<<<dim3(24,24,5), dim3(32,8), 0, stream>>>(Wq,Wk,Wv,W1,W2, Wqkvt,W1t,W2t);

  k_embed<<<ROWS, 192, 0, stream>>>(idx, emb, pos, xbf);

  // QKV projection: [8192][768] x [2304][768]^T -> [8192][2304] bf16  (nwg=1152, %8==0)
  k_gemm2p<0><<<dim3(64,18,1), 256, 0, stream>>>(xbf,768,0L, Wqkvt,768,0L,
                                                 qkv,2304,0L, 768,
                                                 nullptr, nullptr,0, nullptr, 1.0f);

  k_transpose_v<<<dim3(32,24,8), dim3(32,8), 0, stream>>>(qkv, vT);

  // scores + masked exp + fused atomic rowsum -> P (unnormalized, bf16)  (xy nwg=64, %8==0)
  k_gemm2p<3><<<dim3(8,8,8), 256, 0, stream>>>(
      qkv,     2304, (long)SEQ*2304,
      qkv+768, 2304, (long)SEQ*2304,
      P,       SEQ,  (long)SEQ*SEQ,
      768, nullptr, am, SEQ, rsum, 0.03608439182435161f);

  // PV + row normalization: aout = diag(1/rowsum) * (P @ vT^T), bf16  (xy nwg=48, %8==0)
  k_gemm2p<4><<<dim3(8,6,8), 256, 0, stream>>>(
      P,    SEQ, (long)SEQ*SEQ,
      vT,   SEQ, (long)DIM*SEQ,
      aout, DIM, (long)SEQ*DIM,
      1024, nullptr, nullptr,0, rsum, 1.0f);

  k_layernorm<1,1><<<ROWS, 256, 0, stream>>>(aout, ln1g, ln1b, x1);

  // FFN (nwg=384, %8==0)
  k_gemm2p<1><<<dim3(64,6,1), 256, 0, stream>>>(x1,768,0L, W1t,768,0L, h1,768,0L,
                                                768, b1, nullptr,0, nullptr, 1.0f);
  k_gemm2p<1><<<dim3(64,6,1), 256, 0, stream>>>(h1,768,0L, W2t,768,0L, h2,768,0L,
                                                768, b2, nullptr,0, nullptr, 1.0f);

  k_layernorm<1,0><<<ROWS, 256, 0, stream>>>(h2, ln2g, ln2b, out);
}